// Round 4
// baseline (216.433 us; speedup 1.0000x reference)
//
#include <hip/hip_runtime.h>
#include <hip/hip_bf16.h>

// Problem constants (match reference)
constexpr int F_ = 16;        // N_FEATURES
constexpr int K_ = 8;         // NUM_INSTANCES
constexpr int B_ = 16;        // batch
constexpr int HW_ = 512 * 512;
constexpr float DELTA_V = 0.5f;
constexpr float TWO_DELTA_D = 3.0f;   // 2 * 1.5
constexpr float GAMMA = 0.001f;

constexpr int CHUNKS = 64;            // chunks per image
constexpr int PIX = HW_ / CHUNKS;     // 4096 pixels per chunk
constexpr int NBLK = B_ * CHUNKS;     // 1024 blocks (= 4/CU x 256 CU, all co-resident)
constexpr int SLOT = 136;             // per-image accum: 128 sums + 8 counts

// workspace layout (in floats)
constexpr int OFF_SUM  = 0;                      // B*SLOT = 2176 (atomicAdd targets)
constexpr int OFF_MU   = OFF_SUM + B_ * SLOT;    // B*128
constexpr int OFF_INV  = OFF_MU + B_ * 128;      // B*8
constexpr int OFF_IMG  = OFF_INV + B_ * K_;      // B*2 (ldist, lreg)
constexpr int OFF_LVAR = OFF_IMG + 2 * B_;       // B
constexpr int OFF_CTL  = OFF_LVAR + B_;          // 33 u32: ctr[16], flag[16], done

__device__ inline float waveReduceSum(float v) {
#pragma unroll
  for (int off = 32; off > 0; off >>= 1)
    v += __shfl_down(v, off, 64);
  return v;
}

__device__ inline float comp(const float4& v, int i) {
  return i == 0 ? v.x : i == 1 ? v.y : i == 2 ? v.z : v.w;
}

__device__ inline float dload(const float* p) {
  return __hip_atomic_load(p, __ATOMIC_RELAXED, __HIP_MEMORY_SCOPE_AGENT);
}
__device__ inline void dstore(float* p, float v) {
  __hip_atomic_store(p, v, __ATOMIC_RELAXED, __HIP_MEMORY_SCOPE_AGENT);
}

// Zero the atomically-accumulated regions + control words (every call).
__global__ void k0_init(float* __restrict__ ws) {
  const int t = threadIdx.x;
  for (int i = t; i < B_ * SLOT; i += 256) ws[OFF_SUM + i] = 0.f;
  if (t < B_) ws[OFF_LVAR + t] = 0.f;
  unsigned* ctl = (unsigned*)(ws + OFF_CTL);
  if (t < 33) ctl[t] = 0u;
}

__global__ __launch_bounds__(256, 4) void fused(const float* __restrict__ pred,
                                                const int* __restrict__ tgt,
                                                float* __restrict__ ws,
                                                float* __restrict__ out) {
  const int bid = blockIdx.x;
  const int b = bid >> 6, chunk = bid & 63;
  const int t = threadIdx.x;
  const int lane = t & 63, wy = t >> 6;

  float* sum_img = ws + OFF_SUM + b * SLOT;   // 128 sums + 8 counts
  float* mu   = ws + OFF_MU;
  float* invc = ws + OFF_INV;
  float* img  = ws + OFF_IMG;
  float* lvar = ws + OFF_LVAR;
  unsigned* ctl  = (unsigned*)(ws + OFF_CTL);
  unsigned* ctr  = ctl;
  unsigned* flag = ctl + 16;
  unsigned* done = ctl + 32;

  __shared__ alignas(16) float mu_s[8][20];  // 80B rows: 16B-aligned, 8 labs tile 32 banks
  __shared__ float inv_s[8];
  __shared__ float red[4];
  __shared__ int isred;

  const int* tb = tgt + b * HW_ + chunk * PIX;
  const float* pb = pred + (size_t)b * F_ * HW_ + chunk * PIX;

  // ---------------- Phase 1: partial sums/counts, atomicAdd into per-image accum ----
  float acc[4][8];
#pragma unroll
  for (int j = 0; j < 4; ++j)
#pragma unroll
    for (int k = 0; k < 8; ++k) acc[j][k] = 0.f;
  float cnt[8];
#pragma unroll
  for (int k = 0; k < 8; ++k) cnt[k] = 0.f;

  constexpr int ITERS1 = PIX / 256;  // 16
#pragma unroll 1
  for (int it = 0; it < ITERS1; ++it) {
    const int p = it * 256 + lane * 4;
    const int4 lb = *reinterpret_cast<const int4*>(tb + p);
    const int labs[4] = {lb.x, lb.y, lb.z, lb.w};
    float sel[4][8];
#pragma unroll
    for (int pp = 0; pp < 4; ++pp)
#pragma unroll
      for (int k = 0; k < 8; ++k) sel[pp][k] = (labs[pp] == k) ? 1.f : 0.f;

#pragma unroll
    for (int j = 0; j < 4; ++j) {
      const int f = wy * 4 + j;
      const float4 x = *reinterpret_cast<const float4*>(pb + f * HW_ + p);
#pragma unroll
      for (int k = 0; k < 8; ++k) {
        acc[j][k] = fmaf(sel[0][k], x.x, acc[j][k]);
        acc[j][k] = fmaf(sel[1][k], x.y, acc[j][k]);
        acc[j][k] = fmaf(sel[2][k], x.z, acc[j][k]);
        acc[j][k] = fmaf(sel[3][k], x.w, acc[j][k]);
      }
    }
    if (wy == 0) {
#pragma unroll
      for (int k = 0; k < 8; ++k)
        cnt[k] += sel[0][k] + sel[1][k] + sel[2][k] + sel[3][k];
    }
  }

#pragma unroll
  for (int j = 0; j < 4; ++j)
#pragma unroll
    for (int k = 0; k < 8; ++k) {
      float v = waveReduceSum(acc[j][k]);
      if (lane == 0) atomicAdd(&sum_img[k * F_ + wy * 4 + j], v);
    }
  if (wy == 0) {
#pragma unroll
    for (int k = 0; k < 8; ++k) {
      float v = waveReduceSum(cnt[k]);
      if (lane == 0) atomicAdd(&sum_img[128 + k], v);
    }
  }
  __syncthreads();

  // ---------------- Arrival: 64th block of this image becomes reducer ---------------
  if (t == 0) {
    unsigned old = __hip_atomic_fetch_add(&ctr[b], 1u, __ATOMIC_ACQ_REL,
                                          __HIP_MEMORY_SCOPE_AGENT);
    isred = (old == (unsigned)(CHUNKS - 1));
  }
  __syncthreads();

  if (isred) {
    __shared__ float tot[SLOT];
    __shared__ float lreg_sh[8];
    if (t < SLOT) tot[t] = dload(&sum_img[t]);
    __syncthreads();
    if (t < 8) {
      float c = fmaxf(tot[128 + t], 1.f);
      float iv = 1.f / c;
      inv_s[t] = iv;
      dstore(&invc[b * K_ + t], iv);
    }
    __syncthreads();
    if (t < 128) {
      int k = t >> 4, f = t & 15;
      float m = tot[t] * inv_s[k];
      dstore(&mu[b * 128 + t], m);
      mu_s[k][f] = m;
    }
    __syncthreads();
    if (t < 8) {
      float s = 0.f;
#pragma unroll
      for (int f = 0; f < 16; ++f) s = fmaf(mu_s[t][f], mu_s[t][f], s);
      lreg_sh[t] = sqrtf(s);
    }
    if (t < 64) {  // l_dist pairs
      int a = t >> 3, c2 = t & 7;
      float v = 0.f;
      if (a != c2) {
        float dsq = 0.f;
#pragma unroll
        for (int f = 0; f < 16; ++f) {
          float dd = mu_s[a][f] - mu_s[c2][f];
          dsq = fmaf(dd, dd, dsq);
        }
        float h = fmaxf(TWO_DELTA_D - sqrtf(dsq), 0.f);
        v = h * h;
      }
      v = waveReduceSum(v);
      if (t == 0) dstore(&img[b * 2 + 0], v);
    }
    __syncthreads();
    if (t == 0) {
      float lr = 0.f;
#pragma unroll
      for (int k = 0; k < 8; ++k) lr += lreg_sh[k];
      dstore(&img[b * 2 + 1], lr);
      __hip_atomic_store(&flag[b], 1u, __ATOMIC_RELEASE, __HIP_MEMORY_SCOPE_AGENT);
    }
  }

  // ---------------- Spin on this image's flag (all 1024 blocks co-resident) ---------
  if (t == 0) {
    while (__hip_atomic_load(&flag[b], __ATOMIC_ACQUIRE, __HIP_MEMORY_SCOPE_AGENT) == 0u)
      __builtin_amdgcn_s_sleep(2);
  }
  __syncthreads();

  // ---------------- Phase 2: l_var over the SAME chunk, reversed --------------------
  if (t < 128) mu_s[t >> 4][t & 15] = dload(&mu[b * 128 + t]);
  if (t < 8) inv_s[t] = dload(&invc[b * K_ + t]);
  __syncthreads();

  float lsum = 0.f;
  constexpr int ITERS2 = PIX / 1024;  // 4
#pragma unroll 1
  for (int it = ITERS2 - 1; it >= 0; --it) {
    const int p = it * 1024 + t * 4;
    const int4 lb = *reinterpret_cast<const int4*>(tb + p);
    const int labs[4] = {lb.x, lb.y, lb.z, lb.w};
    float d2[4] = {0.f, 0.f, 0.f, 0.f};
#pragma unroll
    for (int f4 = 0; f4 < 4; ++f4) {
      const float4 xr0 = *reinterpret_cast<const float4*>(pb + (f4 * 4 + 0) * HW_ + p);
      const float4 xr1 = *reinterpret_cast<const float4*>(pb + (f4 * 4 + 1) * HW_ + p);
      const float4 xr2 = *reinterpret_cast<const float4*>(pb + (f4 * 4 + 2) * HW_ + p);
      const float4 xr3 = *reinterpret_cast<const float4*>(pb + (f4 * 4 + 3) * HW_ + p);
#pragma unroll
      for (int pp = 0; pp < 4; ++pp) {
        const float4 m = *reinterpret_cast<const float4*>(&mu_s[labs[pp]][f4 * 4]);
        float e0 = comp(xr0, pp) - m.x;
        float e1 = comp(xr1, pp) - m.y;
        float e2 = comp(xr2, pp) - m.z;
        float e3 = comp(xr3, pp) - m.w;
        float s = fmaf(e0, e0, 0.f);
        s = fmaf(e1, e1, s);
        s = fmaf(e2, e2, s);
        s = fmaf(e3, e3, s);
        d2[pp] += s;
      }
    }
#pragma unroll
    for (int pp = 0; pp < 4; ++pp) {
      float dist = sqrtf(d2[pp]);
      float h = fmaxf(dist - DELTA_V, 0.f);
      lsum = fmaf(h * h, inv_s[labs[pp]], lsum);
    }
  }
  float v = waveReduceSum(lsum);
  if (lane == 0) red[wy] = v;
  __syncthreads();

  // ---------------- Completion: last block finalizes --------------------------------
  if (t == 0) {
    atomicAdd(&lvar[b], red[0] + red[1] + red[2] + red[3]);
    unsigned d = __hip_atomic_fetch_add(done, 1u, __ATOMIC_ACQ_REL,
                                        __HIP_MEMORY_SCOPE_AGENT);
    if (d == (unsigned)(NBLK - 1)) {
      float lv = 0.f, ld = 0.f, lr = 0.f;
#pragma unroll
      for (int bb = 0; bb < B_; ++bb) {
        lv += dload(&lvar[bb]);
        ld += dload(&img[bb * 2 + 0]);
        lr += dload(&img[bb * 2 + 1]);
      }
      lv *= 1.f / (K_ * (float)B_);
      ld *= 1.f / (K_ * (K_ - 1) * (float)B_);
      lr *= 1.f / (K_ * (float)B_);
      out[0] = lv + ld + GAMMA * lr;
      out[1] = lv;
      out[2] = ld;
      out[3] = lr;
    }
  }
}

extern "C" void kernel_launch(void* const* d_in, const int* in_sizes, int n_in,
                              void* d_out, int out_size, void* d_ws, size_t ws_size,
                              hipStream_t stream) {
  const float* pred = (const float*)d_in[0];
  const int* tgt = (const int*)d_in[1];
  float* out = (float*)d_out;
  float* ws = (float*)d_ws;

  hipLaunchKernelGGL(k0_init, dim3(1), dim3(256), 0, stream, ws);
  hipLaunchKernelGGL(fused, dim3(NBLK), dim3(256), 0, stream, pred, tgt, ws, out);
}

// Round 6
// 197.097 us; speedup vs baseline: 1.0981x; 1.0981x over previous
//
#include <hip/hip_runtime.h>
#include <hip/hip_bf16.h>

// Problem constants (match reference)
constexpr int F_ = 16;        // N_FEATURES
constexpr int K_ = 8;         // NUM_INSTANCES
constexpr int B_ = 16;        // batch
constexpr int HW_ = 512 * 512;
constexpr float DELTA_V = 0.5f;
constexpr float TWO_DELTA_D = 3.0f;   // 2 * 1.5
constexpr float GAMMA = 0.001f;

constexpr int CHUNKS = 64;            // chunks per image
constexpr int PIX = HW_ / CHUNKS;     // 4096 pixels per chunk
constexpr int NBLK = B_ * CHUNKS;     // 1024 blocks (= 4/CU x 256 CU, co-resident)
constexpr int SLOT = 136;             // per-image accum: 128 sums + 8 counts

// workspace layout (in floats)
constexpr int OFF_SUM  = 0;                      // B*SLOT (atomicAdd targets)
constexpr int OFF_MU   = OFF_SUM + B_ * SLOT;    // B*128
constexpr int OFF_INV  = OFF_MU + B_ * 128;      // B*8
constexpr int OFF_IMG  = OFF_INV + B_ * K_;      // B*2 (ldist, lreg)
constexpr int OFF_LVAR = OFF_IMG + 2 * B_;       // B
constexpr int OFF_CTL  = OFF_LVAR + B_;          // 33 u32: ctr[16], flag[16], done

__device__ inline float waveReduceSum(float v) {
#pragma unroll
  for (int off = 32; off > 0; off >>= 1)
    v += __shfl_down(v, off, 64);
  return v;
}

__device__ inline float comp(const float4& v, int i) {
  return i == 0 ? v.x : i == 1 ? v.y : i == 2 ? v.z : v.w;
}

__device__ inline float dload(const float* p) {
  return __hip_atomic_load(p, __ATOMIC_RELAXED, __HIP_MEMORY_SCOPE_AGENT);
}
__device__ inline void dstore(float* p, float v) {
  __hip_atomic_store(p, v, __ATOMIC_RELAXED, __HIP_MEMORY_SCOPE_AGENT);
}

// Zero the atomically-accumulated regions + control words (every call).
__global__ void k0_init(float* __restrict__ ws) {
  const int t = threadIdx.x;
  for (int i = t; i < B_ * SLOT; i += 256) ws[OFF_SUM + i] = 0.f;
  if (t < B_) ws[OFF_LVAR + t] = 0.f;
  unsigned* ctl = (unsigned*)(ws + OFF_CTL);
  if (t < 33) ctl[t] = 0u;
}

__global__ __launch_bounds__(256, 4) void fused(const float* __restrict__ pred,
                                                const int* __restrict__ tgt,
                                                float* __restrict__ ws,
                                                float* __restrict__ out) {
  const int bid = blockIdx.x;
  const int b = bid >> 6, chunk = bid & 63;
  const int t = threadIdx.x;
  const int lane = t & 63, wy = t >> 6;

  float* sum_img = ws + OFF_SUM + b * SLOT;   // 128 sums + 8 counts
  float* mu   = ws + OFF_MU;
  float* invc = ws + OFF_INV;
  float* img  = ws + OFF_IMG;
  float* lvar = ws + OFF_LVAR;
  unsigned* ctl  = (unsigned*)(ws + OFF_CTL);
  unsigned* ctr  = ctl;
  unsigned* flag = ctl + 16;
  unsigned* done = ctl + 32;

  __shared__ alignas(16) float mu_s[8][20];  // 80B rows: 16B-aligned, 8 labs tile 32 banks
  __shared__ float inv_s[8];
  __shared__ float red[4];
  __shared__ int isred;

  const int* tb = tgt + b * HW_ + chunk * PIX;
  const float* pb = pred + (size_t)b * F_ * HW_ + chunk * PIX;

  // ---------------- Phase 1: partial sums/counts, atomicAdd into per-image accum ----
  float acc[4][8];
#pragma unroll
  for (int j = 0; j < 4; ++j)
#pragma unroll
    for (int k = 0; k < 8; ++k) acc[j][k] = 0.f;
  float cnt[8];
#pragma unroll
  for (int k = 0; k < 8; ++k) cnt[k] = 0.f;

  constexpr int ITERS1 = PIX / 256;  // 16
#pragma unroll 1
  for (int it = 0; it < ITERS1; ++it) {
    const int p = it * 256 + lane * 4;
    const int4 lb = *reinterpret_cast<const int4*>(tb + p);
    // issue all 4 pred loads before consumption
    float4 xr[4];
#pragma unroll
    for (int j = 0; j < 4; ++j)
      xr[j] = *reinterpret_cast<const float4*>(pb + (wy * 4 + j) * HW_ + p);

    const int labs[4] = {lb.x, lb.y, lb.z, lb.w};
    float sel[4][8];
#pragma unroll
    for (int pp = 0; pp < 4; ++pp)
#pragma unroll
      for (int k = 0; k < 8; ++k) sel[pp][k] = (labs[pp] == k) ? 1.f : 0.f;

#pragma unroll
    for (int j = 0; j < 4; ++j) {
#pragma unroll
      for (int k = 0; k < 8; ++k) {
        acc[j][k] = fmaf(sel[0][k], xr[j].x, acc[j][k]);
        acc[j][k] = fmaf(sel[1][k], xr[j].y, acc[j][k]);
        acc[j][k] = fmaf(sel[2][k], xr[j].z, acc[j][k]);
        acc[j][k] = fmaf(sel[3][k], xr[j].w, acc[j][k]);
      }
    }
    if (wy == 0) {
#pragma unroll
      for (int k = 0; k < 8; ++k)
        cnt[k] += sel[0][k] + sel[1][k] + sel[2][k] + sel[3][k];
    }
  }

#pragma unroll
  for (int j = 0; j < 4; ++j)
#pragma unroll
    for (int k = 0; k < 8; ++k) {
      float v = waveReduceSum(acc[j][k]);
      if (lane == 0) atomicAdd(&sum_img[k * F_ + wy * 4 + j], v);
    }
  if (wy == 0) {
#pragma unroll
    for (int k = 0; k < 8; ++k) {
      float v = waveReduceSum(cnt[k]);
      if (lane == 0) atomicAdd(&sum_img[128 + k], v);
    }
  }
  __syncthreads();

  // ---------------- Arrival: 64th block of this image becomes reducer ---------------
  if (t == 0) {
    unsigned old = __hip_atomic_fetch_add(&ctr[b], 1u, __ATOMIC_ACQ_REL,
                                          __HIP_MEMORY_SCOPE_AGENT);
    isred = (old == (unsigned)(CHUNKS - 1));
  }
  __syncthreads();

  if (isred) {
    __shared__ float tot[SLOT];
    __shared__ float lreg_sh[8];
    if (t < SLOT) tot[t] = dload(&sum_img[t]);
    __syncthreads();
    if (t < 8) {
      float c = fmaxf(tot[128 + t], 1.f);
      float iv = 1.f / c;
      inv_s[t] = iv;
      dstore(&invc[b * K_ + t], iv);
    }
    __syncthreads();
    if (t < 128) {
      int k = t >> 4, f = t & 15;
      float m = tot[t] * inv_s[k];
      dstore(&mu[b * 128 + t], m);
      mu_s[k][f] = m;
    }
    __syncthreads();
    if (t < 8) {
      float s = 0.f;
#pragma unroll
      for (int f = 0; f < 16; ++f) s = fmaf(mu_s[t][f], mu_s[t][f], s);
      lreg_sh[t] = sqrtf(s);
    }
    if (t < 64) {  // l_dist pairs
      int a = t >> 3, c2 = t & 7;
      float v = 0.f;
      if (a != c2) {
        float dsq = 0.f;
#pragma unroll
        for (int f = 0; f < 16; ++f) {
          float dd = mu_s[a][f] - mu_s[c2][f];
          dsq = fmaf(dd, dd, dsq);
        }
        float h = fmaxf(TWO_DELTA_D - sqrtf(dsq), 0.f);
        v = h * h;
      }
      v = waveReduceSum(v);
      if (t == 0) dstore(&img[b * 2 + 0], v);
    }
    __syncthreads();
    if (t == 0) {
      float lr = 0.f;
#pragma unroll
      for (int k = 0; k < 8; ++k) lr += lreg_sh[k];
      dstore(&img[b * 2 + 1], lr);
      __hip_atomic_store(&flag[b], 1u, __ATOMIC_RELEASE, __HIP_MEMORY_SCOPE_AGENT);
    }
  }

  // ---------------- Spin (RELAXED) on this image's flag; one acquire fence after ----
  if (t == 0) {
    while (__hip_atomic_load(&flag[b], __ATOMIC_RELAXED, __HIP_MEMORY_SCOPE_AGENT) == 0u)
      __builtin_amdgcn_s_sleep(8);
    __builtin_amdgcn_fence(__ATOMIC_ACQUIRE, "agent");
  }
  __syncthreads();

  // ---------------- Phase 2: l_var over the SAME chunk, reversed --------------------
  if (t < 128) mu_s[t >> 4][t & 15] = dload(&mu[b * 128 + t]);
  if (t < 8) inv_s[t] = dload(&invc[b * K_ + t]);
  __syncthreads();

  float lsum = 0.f;
  constexpr int ITERS2 = PIX / 1024;  // 4
#pragma unroll 1
  for (int it = ITERS2 - 1; it >= 0; --it) {
    const int p = it * 1024 + t * 4;
    const int4 lb = *reinterpret_cast<const int4*>(tb + p);
    // issue ALL 16 pred loads before any consumption (MLP: 1KB/wave in flight)
    float4 xr[16];
#pragma unroll
    for (int f = 0; f < 16; ++f)
      xr[f] = *reinterpret_cast<const float4*>(pb + f * HW_ + p);

    const int labs[4] = {lb.x, lb.y, lb.z, lb.w};
    float d2[4] = {0.f, 0.f, 0.f, 0.f};
#pragma unroll
    for (int pp = 0; pp < 4; ++pp) {
      const float* mrow = &mu_s[labs[pp]][0];
#pragma unroll
      for (int f4 = 0; f4 < 4; ++f4) {
        const float4 m = *reinterpret_cast<const float4*>(mrow + f4 * 4);
        float e0 = comp(xr[f4 * 4 + 0], pp) - m.x;
        float e1 = comp(xr[f4 * 4 + 1], pp) - m.y;
        float e2 = comp(xr[f4 * 4 + 2], pp) - m.z;
        float e3 = comp(xr[f4 * 4 + 3], pp) - m.w;
        float s = fmaf(e0, e0, 0.f);
        s = fmaf(e1, e1, s);
        s = fmaf(e2, e2, s);
        s = fmaf(e3, e3, s);
        d2[pp] += s;
      }
    }
#pragma unroll
    for (int pp = 0; pp < 4; ++pp) {
      float dist = sqrtf(d2[pp]);
      float h = fmaxf(dist - DELTA_V, 0.f);
      lsum = fmaf(h * h, inv_s[labs[pp]], lsum);
    }
  }
  float v = waveReduceSum(lsum);
  if (lane == 0) red[wy] = v;
  __syncthreads();

  // ---------------- Completion: last block finalizes --------------------------------
  if (t == 0) {
    atomicAdd(&lvar[b], red[0] + red[1] + red[2] + red[3]);
    unsigned d = __hip_atomic_fetch_add(done, 1u, __ATOMIC_ACQ_REL,
                                        __HIP_MEMORY_SCOPE_AGENT);
    if (d == (unsigned)(NBLK - 1)) {
      float lv = 0.f, ld = 0.f, lr = 0.f;
#pragma unroll
      for (int bb = 0; bb < B_; ++bb) {
        lv += dload(&lvar[bb]);
        ld += dload(&img[bb * 2 + 0]);
        lr += dload(&img[bb * 2 + 1]);
      }
      lv *= 1.f / (K_ * (float)B_);
      ld *= 1.f / (K_ * (K_ - 1) * (float)B_);
      lr *= 1.f / (K_ * (float)B_);
      out[0] = lv + ld + GAMMA * lr;
      out[1] = lv;
      out[2] = ld;
      out[3] = lr;
    }
  }
}

extern "C" void kernel_launch(void* const* d_in, const int* in_sizes, int n_in,
                              void* d_out, int out_size, void* d_ws, size_t ws_size,
                              hipStream_t stream) {
  const float* pred = (const float*)d_in[0];
  const int* tgt = (const int*)d_in[1];
  float* out = (float*)d_out;
  float* ws = (float*)d_ws;

  hipLaunchKernelGGL(k0_init, dim3(1), dim3(256), 0, stream, ws);
  hipLaunchKernelGGL(fused, dim3(NBLK), dim3(256), 0, stream, pred, tgt, ws, out);
}

// Round 7
// 106.480 us; speedup vs baseline: 2.0326x; 1.8510x over previous
//
#include <hip/hip_runtime.h>
#include <hip/hip_bf16.h>

// Problem constants (match reference)
constexpr int F_ = 16;        // N_FEATURES
constexpr int K_ = 8;         // NUM_INSTANCES
constexpr int B_ = 16;        // batch
constexpr int HW_ = 512 * 512;
constexpr float DELTA_V = 0.5f;
constexpr float TWO_DELTA_D = 3.0f;   // 2 * 1.5
constexpr float GAMMA = 0.001f;

constexpr int CHUNKS = 64;            // chunks per image
constexpr int PIX = HW_ / CHUNKS;     // 4096 pixels per chunk
constexpr int SLOT = 136;             // per-block partial: 128 sums + 8 counts
constexpr int NPART = B_ * CHUNKS;    // 1024 blocks

// workspace layout (in floats)
constexpr int OFF_PART = 0;                          // NPART*SLOT
constexpr int OFF_MU   = OFF_PART + NPART * SLOT;    // B*128
constexpr int OFF_INV  = OFF_MU + B_ * 128;          // B*8
constexpr int OFF_IMG  = OFF_INV + B_ * K_;          // B*2 (ldist, lreg)
constexpr int OFF_LVAR = OFF_IMG + 2 * B_;           // B (zeroed by k2)

__device__ inline float waveReduceSum(float v) {
#pragma unroll
  for (int off = 32; off > 0; off >>= 1)
    v += __shfl_down(v, off, 64);
  return v;
}

__device__ inline float comp(const float4& v, int i) {
  return i == 0 ? v.x : i == 1 ? v.y : i == 2 ? v.z : v.w;
}

// Pass 1: per-(image,chunk) partial counts + feature sums -> ws slots (no atomics).
// grid (CHUNKS, B), block (64, 4): wave wy owns features [4*wy, 4*wy+4)
__global__ __launch_bounds__(256) void k1_sums(const float* __restrict__ pred,
                                               const int* __restrict__ tgt,
                                               float* __restrict__ ws) {
  float* part = ws + OFF_PART;
  const int b = blockIdx.y;
  const int chunk = blockIdx.x;
  const int lane = threadIdx.x;   // 0..63
  const int wy = threadIdx.y;     // 0..3

  float acc[4][8];
#pragma unroll
  for (int j = 0; j < 4; ++j)
#pragma unroll
    for (int k = 0; k < 8; ++k) acc[j][k] = 0.f;
  float cnt[8];
#pragma unroll
  for (int k = 0; k < 8; ++k) cnt[k] = 0.f;

  const int* tb = tgt + b * HW_ + chunk * PIX;
  const float* pb = pred + (size_t)b * F_ * HW_ + chunk * PIX;

  constexpr int ITERS = PIX / 256;  // 16 (64 lanes x 4 pixels per iter)
#pragma unroll 1
  for (int it = 0; it < ITERS; ++it) {
    const int p = it * 256 + lane * 4;
    const int4 lb = *reinterpret_cast<const int4*>(tb + p);
    // issue all pred loads before consumption
    float4 xr[4];
#pragma unroll
    for (int j = 0; j < 4; ++j)
      xr[j] = *reinterpret_cast<const float4*>(pb + (wy * 4 + j) * HW_ + p);

    const int labs[4] = {lb.x, lb.y, lb.z, lb.w};
    float sel[4][8];
#pragma unroll
    for (int pp = 0; pp < 4; ++pp)
#pragma unroll
      for (int k = 0; k < 8; ++k) sel[pp][k] = (labs[pp] == k) ? 1.f : 0.f;

#pragma unroll
    for (int j = 0; j < 4; ++j) {
#pragma unroll
      for (int k = 0; k < 8; ++k) {
        acc[j][k] = fmaf(sel[0][k], xr[j].x, acc[j][k]);
        acc[j][k] = fmaf(sel[1][k], xr[j].y, acc[j][k]);
        acc[j][k] = fmaf(sel[2][k], xr[j].z, acc[j][k]);
        acc[j][k] = fmaf(sel[3][k], xr[j].w, acc[j][k]);
      }
    }
    if (wy == 0) {
#pragma unroll
      for (int k = 0; k < 8; ++k)
        cnt[k] += sel[0][k] + sel[1][k] + sel[2][k] + sel[3][k];
    }
  }

  float* slot = part + (size_t)(b * CHUNKS + chunk) * SLOT;
#pragma unroll
  for (int j = 0; j < 4; ++j)
#pragma unroll
    for (int k = 0; k < 8; ++k) {
      float v = waveReduceSum(acc[j][k]);
      if (lane == 0) slot[k * F_ + wy * 4 + j] = v;
    }
  if (wy == 0) {
#pragma unroll
    for (int k = 0; k < 8; ++k) {
      float v = waveReduceSum(cnt[k]);
      if (lane == 0) slot[128 + k] = v;
    }
  }
}

// Reduce partials -> mu, inv; per-image l_dist + l_reg; zero lvar accumulators.
// grid B, block 256.
__global__ __launch_bounds__(256) void k2_mu(float* __restrict__ ws) {
  const float* part = ws + OFF_PART;
  float* invc = ws + OFF_INV;
  float* mu = ws + OFF_MU;
  float* img = ws + OFF_IMG;
  float* lvar = ws + OFF_LVAR;
  const int b = blockIdx.x, t = threadIdx.x;
  __shared__ float tot[SLOT];
  __shared__ float mu_s[8][17];
  __shared__ float inv_s[8];
  __shared__ float lreg_arr[8];

  if (t < B_ && b == 0) lvar[t] = 0.f;   // zeroed before k3 (stream order)

  if (t < SLOT) {
    float s = 0.f;
    const float* p = part + (size_t)b * CHUNKS * SLOT + t;
    for (int c = 0; c < CHUNKS; ++c) s += p[(size_t)c * SLOT];
    tot[t] = s;
  }
  __syncthreads();
  if (t < 8) {
    float c = fmaxf(tot[128 + t], 1.f);
    float iv = 1.f / c;
    inv_s[t] = iv;
    invc[b * K_ + t] = iv;
  }
  __syncthreads();
  if (t < 128) {
    int k = t >> 4, f = t & 15;
    float m = tot[t] * inv_s[k];
    mu[b * 128 + t] = m;
    mu_s[k][f] = m;
  }
  __syncthreads();
  if (t < 8) {  // l_reg partial: ||mu_k||
    float s = 0.f;
#pragma unroll
    for (int f = 0; f < 16; ++f) s = fmaf(mu_s[t][f], mu_s[t][f], s);
    lreg_arr[t] = sqrtf(s);
  }
  if (t < 64) {  // l_dist: pair (a,c)
    int a = t >> 3, c2 = t & 7;
    float v = 0.f;
    if (a != c2) {
      float dsq = 0.f;
#pragma unroll
      for (int f = 0; f < 16; ++f) {
        float dd = mu_s[a][f] - mu_s[c2][f];
        dsq = fmaf(dd, dd, dsq);
      }
      float h = fmaxf(TWO_DELTA_D - sqrtf(dsq), 0.f);
      v = h * h;
    }
    v = waveReduceSum(v);
    if (t == 0) img[b * 2 + 0] = v;
  }
  __syncthreads();
  if (t == 0) {
    float lr = 0.f;
#pragma unroll
    for (int k = 0; k < 8; ++k) lr += lreg_arr[k];
    img[b * 2 + 1] = lr;
  }
}

// Pass 2: l_var. grid (CHUNKS, B), block 256 flat; 16 loads hoisted per iter.
__global__ __launch_bounds__(256) void k3_lvar(const float* __restrict__ pred,
                                               const int* __restrict__ tgt,
                                               float* __restrict__ ws) {
  const float* mu = ws + OFF_MU;
  const float* inv = ws + OFF_INV;
  float* lvar = ws + OFF_LVAR;
  const int b = blockIdx.y, chunk = blockIdx.x;
  const int t = threadIdx.x;
  __shared__ alignas(16) float mu_s[8][20];  // 80B rows: 16B aligned, banks spread
  __shared__ float inv_s[8];
  __shared__ float red[4];
  if (t < 128) mu_s[t >> 4][t & 15] = mu[b * 128 + t];
  if (t < 8) inv_s[t] = inv[b * K_ + t];
  __syncthreads();

  const int* tb = tgt + b * HW_ + chunk * PIX;
  const float* pb = pred + (size_t)b * F_ * HW_ + chunk * PIX;

  float lsum = 0.f;
  constexpr int ITERS = PIX / 1024;  // 4 (256 threads x 4 pixels)
#pragma unroll 1
  for (int it = ITERS - 1; it >= 0; --it) {   // reverse: re-read k1's hottest data first
    const int p = it * 1024 + t * 4;
    const int4 lb = *reinterpret_cast<const int4*>(tb + p);
    // issue ALL 16 pred loads before any consumption (1KB/lane-group in flight)
    float4 xr[16];
#pragma unroll
    for (int f = 0; f < 16; ++f)
      xr[f] = *reinterpret_cast<const float4*>(pb + f * HW_ + p);

    const int labs[4] = {lb.x, lb.y, lb.z, lb.w};
    float d2[4] = {0.f, 0.f, 0.f, 0.f};
#pragma unroll
    for (int pp = 0; pp < 4; ++pp) {
      const float* mrow = &mu_s[labs[pp]][0];
#pragma unroll
      for (int f4 = 0; f4 < 4; ++f4) {
        const float4 m = *reinterpret_cast<const float4*>(mrow + f4 * 4);
        float e0 = comp(xr[f4 * 4 + 0], pp) - m.x;
        float e1 = comp(xr[f4 * 4 + 1], pp) - m.y;
        float e2 = comp(xr[f4 * 4 + 2], pp) - m.z;
        float e3 = comp(xr[f4 * 4 + 3], pp) - m.w;
        float s = fmaf(e0, e0, 0.f);
        s = fmaf(e1, e1, s);
        s = fmaf(e2, e2, s);
        s = fmaf(e3, e3, s);
        d2[pp] += s;
      }
    }
#pragma unroll
    for (int pp = 0; pp < 4; ++pp) {
      float dist = sqrtf(d2[pp]);
      float h = fmaxf(dist - DELTA_V, 0.f);
      lsum = fmaf(h * h, inv_s[labs[pp]], lsum);
    }
  }
  float v = waveReduceSum(lsum);
  const int lane = t & 63, wid = t >> 6;
  if (lane == 0) red[wid] = v;
  __syncthreads();
  if (t == 0) atomicAdd(&lvar[b], red[0] + red[1] + red[2] + red[3]);
}

__global__ void k4_final(const float* __restrict__ ws, float* __restrict__ out) {
  const float* img = ws + OFF_IMG;
  const float* lvar = ws + OFF_LVAR;
  float lv = 0.f, ld = 0.f, lr = 0.f;
#pragma unroll
  for (int b = 0; b < B_; ++b) {
    lv += lvar[b];
    ld += img[b * 2 + 0];
    lr += img[b * 2 + 1];
  }
  lv *= 1.f / (K_ * (float)B_);
  ld *= 1.f / (K_ * (K_ - 1) * (float)B_);
  lr *= 1.f / (K_ * (float)B_);
  out[0] = lv + ld + GAMMA * lr;
  out[1] = lv;
  out[2] = ld;
  out[3] = lr;
}

extern "C" void kernel_launch(void* const* d_in, const int* in_sizes, int n_in,
                              void* d_out, int out_size, void* d_ws, size_t ws_size,
                              hipStream_t stream) {
  const float* pred = (const float*)d_in[0];
  const int* tgt = (const int*)d_in[1];
  float* out = (float*)d_out;
  float* ws = (float*)d_ws;

  hipLaunchKernelGGL(k1_sums, dim3(CHUNKS, B_), dim3(64, 4), 0, stream, pred, tgt, ws);
  hipLaunchKernelGGL(k2_mu, dim3(B_), dim3(256), 0, stream, ws);
  hipLaunchKernelGGL(k3_lvar, dim3(CHUNKS, B_), dim3(256), 0, stream, pred, tgt, ws);
  hipLaunchKernelGGL(k4_final, dim3(1), dim3(1), 0, stream, ws, out);
}